// Round 7
// baseline (775.927 us; speedup 1.0000x reference)
//
#include <hip/hip_runtime.h>
#include <math.h>

#define BB 16
#define TT 2048
#define FF 512
#define NBLK_WT 8192         // wt blocks: 4 rows (waves) per block
#define ACTIVE_BLOCKS 4096   // pool rows j<1024, 1 wave/row
#define ZERO_BLOCKS   1024   // rows j in [1024,2048): always zero (counts <= 1024)
#define MASK_BLOCKS   32

typedef float v4f __attribute__((ext_vector_type(4)));

// K1: wt + (fused) seg via last-16-blocks-done ticket.
__global__ __launch_bounds__(256) void wt_seg_kernel(const float* __restrict__ x,
                                                     const float* __restrict__ w,
                                                     const float* __restrict__ bias,
                                                     float* __restrict__ wt,
                                                     int* __restrict__ starts,
                                                     int* __restrict__ ends,
                                                     int* __restrict__ counts,
                                                     unsigned int* __restrict__ counter) {
    int tid  = threadIdx.x;
    int gid  = blockIdx.x * 256 + tid;
    int row  = gid >> 6;     // one wave per row
    int lane = gid & 63;
    {
        const float* xr = x + (size_t)row * FF + lane * 8;
        const float* wr = w + lane * 8;
        float4 a0 = *(const float4*)xr;
        float4 a1 = *(const float4*)(xr + 4);
        float4 w0 = *(const float4*)wr;
        float4 w1 = *(const float4*)(wr + 4);
        float s = a0.x * w0.x + a0.y * w0.y + a0.z * w0.z + a0.w * w0.w
                + a1.x * w1.x + a1.y * w1.y + a1.z * w1.z + a1.w * w1.w;
#pragma unroll
        for (int off = 32; off > 0; off >>= 1) s += __shfl_xor(s, off, 64);
        if (lane == 0) wt[row] = 1.0f / (1.0f + expf(-(s + bias[0])));
    }

    // ---- ticket: last 16 blocks (by completion order) each run seg for one batch ----
    __shared__ unsigned int sticket;
    __threadfence();                       // make this block's wt stores device-visible
    __syncthreads();
    if (tid == 0) sticket = atomicAdd(counter, 1u);
    __syncthreads();
    unsigned int ticket = sticket;
    if (ticket < (unsigned)(NBLK_WT - 16)) return;
    if (tid == 0) {
        while (atomicAdd(counter, 0u) < (unsigned)NBLK_WT) __builtin_amdgcn_s_sleep(1);
    }
    __syncthreads();
    __threadfence();                       // acquire: all wt now visible
    if (tid >= 64) return;
    int b    = (int)(ticket - (NBLK_WT - 16));
    int sl   = tid;                        // lane 0..63, 32 positions each
    const float* wrow = wt + b * TT;
    float v[32];
    const float4* p = (const float4*)(wrow + sl * 32);
#pragma unroll
    for (int k = 0; k < 8; ++k) {
        float4 f = p[k];
        v[4*k] = f.x; v[4*k+1] = f.y; v[4*k+2] = f.z; v[4*k+3] = f.w;
    }
    float left  = __shfl_up(v[31], 1, 64);
    float right = __shfl_down(v[0], 1, 64);
    unsigned int flags = 0;
#pragma unroll
    for (int k = 0; k < 32; ++k) {
        int t = sl * 32 + k;
        float prev = (k == 0)  ? left  : v[k - 1];
        float next = (k == 31) ? right : v[k + 1];
        bool val = (t > 0) && (t < TT - 1) && (v[k] < prev) && (v[k] < next);
        if (val) flags |= (1u << k);
    }
    int cnt = __popc(flags);
    int inc = cnt;
#pragma unroll
    for (int off = 1; off < 64; off <<= 1) {
        int y = __shfl_up(inc, off, 64);
        if (sl >= off) inc += y;
    }
    int total = __shfl(inc, 63, 64);
    int r = inc - cnt;
    int* sb = starts + b * TT;
    int* eb = ends + b * TT;
    unsigned int f = flags;
    while (f) {
        int k = __ffs(f) - 1;
        f &= f - 1;
        int t = sl * 32 + k;
        sb[r + 1] = t;
        eb[r] = t + 2;                     // t <= 2046 -> t+2 <= TT
        ++r;
    }
    if (sl == 0) {
        sb[0] = 0;
        eb[total] = TT;
        counts[b] = total + 1;
    }
}

// K2: partitioned pool (unroll-8 gather) + zero region + mask.
__global__ __launch_bounds__(256) void pool_kernel(const float* __restrict__ x,
                                                   const float* __restrict__ wt,
                                                   const int* __restrict__ starts,
                                                   const int* __restrict__ ends,
                                                   const int* __restrict__ counts,
                                                   const int* __restrict__ seq_len,
                                                   float* __restrict__ out,
                                                   float* __restrict__ mask_out) {
    int blk = blockIdx.x;
    int tid = threadIdx.x;
    v4f zero = (v4f)(0.f);

    if (blk >= ACTIVE_BLOCKS + ZERO_BLOCKS) {
        // ---- mask ----
        int idx = (blk - ACTIVE_BLOCKS - ZERO_BLOCKS) * 256 + tid;  // [0, 8192)
        int maxc = 0;
#pragma unroll
        for (int i = 0; i < BB; ++i) maxc = max(maxc, counts[i]);
        float len0 = (float)min(seq_len[0], TT);
#pragma unroll
        for (int r = 0; r < 4; ++r) {
            int i = idx + r * 8192;
            int b = i >> 11, t = i & (TT - 1);
            int nl = (int)((float)min(seq_len[b], TT) / len0 * (float)maxc);
            mask_out[i] = (t < nl) ? 1.0f : 0.0f;
        }
        return;
    }

    if (blk >= ACTIVE_BLOCKS) {
        // ---- zero region: rows j in [1024, 2048), 16 rows per block ----
        int zb = blk - ACTIVE_BLOCKS;
        int b  = zb >> 6;
        int j0 = 1024 + (zb & 63) * 16;
        float* base = out + ((size_t)(b * TT + j0) * FF);
        v4f* dst = (v4f*)base + tid * 2;
        __builtin_nontemporal_store(zero, dst);
        __builtin_nontemporal_store(zero, dst + 1);
        return;
    }

    // ---- active pool: 4 waves/block, 1 wave/row, j in [0,1024) ----
    int b    = blk >> 8;
    int wv   = tid >> 6;
    int lane = tid & 63;
    int j    = (blk & 255) * 4 + wv;
    int row  = b * TT + j;
    float* orow = out + (size_t)row * FF + lane * 8;

    v4f acc0 = (v4f)(0.f);
    v4f acc1 = (v4f)(0.f);
    if (j < counts[b]) {
        int s = __builtin_amdgcn_readfirstlane(starts[row]);
        int e = __builtin_amdgcn_readfirstlane(ends[row]);
        const float* xb   = x + (size_t)b * TT * FF + lane * 8;
        const float* wrow = wt + b * TT;
        float den = 0.f;
        for (int t = s; t < e; t += 8) {
            int   ii[8];
            float ww[8];
#pragma unroll
            for (int k = 0; k < 8; ++k) {
                int tt = t + k;
                bool in = (tt < e);
                ii[k] = in ? tt : t;
                ww[k] = in ? wrow[ii[k]] : 0.f;
            }
#pragma unroll
            for (int k = 0; k < 8; ++k) {
                const v4f* p = (const v4f*)(xb + (size_t)ii[k] * FF);
                v4f v0 = p[0], v1 = p[1];
                acc0 += ww[k] * v0;
                acc1 += ww[k] * v1;
                den  += ww[k];
            }
        }
        float inv = 1.0f / fmaxf(den, 1e-6f);
        acc0 *= inv; acc1 *= inv;
    }
    __builtin_nontemporal_store(acc0, (v4f*)orow);
    __builtin_nontemporal_store(acc1, (v4f*)(orow + 4));
}

extern "C" void kernel_launch(void* const* d_in, const int* in_sizes, int n_in,
                              void* d_out, int out_size, void* d_ws, size_t ws_size,
                              hipStream_t stream) {
    const float* x       = (const float*)d_in[0];
    const float* w_aggr  = (const float*)d_in[1];
    const float* b_aggr  = (const float*)d_in[2];
    const int*   seq_len = (const int*)d_in[3];

    float* pooled = (float*)d_out;
    float* mask   = (float*)d_out + (size_t)BB * TT * FF;

    // ws: wt [B*T] f32 | starts [B*T] i32 | ends [B*T] i32 | counts [BB] i32 | counter u32
    float* wt    = (float*)d_ws;
    int* starts  = (int*)((char*)d_ws + (size_t)BB * TT * 4);
    int* ends    = starts + BB * TT;
    int* counts  = ends + BB * TT;
    unsigned int* counter = (unsigned int*)(counts + BB);

    hipMemsetAsync(counter, 0, 4, stream);
    wt_seg_kernel<<<NBLK_WT, 256, 0, stream>>>(x, w_aggr, b_aggr, wt, starts, ends,
                                               counts, counter);
    pool_kernel<<<ACTIVE_BLOCKS + ZERO_BLOCKS + MASK_BLOCKS, 256, 0, stream>>>(
        x, wt, starts, ends, counts, seq_len, pooled, mask);
}

// Round 8
// 130.309 us; speedup vs baseline: 5.9545x; 5.9545x over previous
//
#include <hip/hip_runtime.h>
#include <math.h>

#define BB 16
#define TT 2048
#define FF 512

#define PAIR_BLOCKS 2048     // 16 batches x 128 blocks; 4 waves/block; 1 wave = rows (2p, 2p+1), p<512
#define ZERO_BLOCKS 1024     // rows j in [1024,2048): always zero (counts <= 1024), 16 rows/block
#define MASK_BLOCKS 32

typedef float v4f __attribute__((ext_vector_type(4)));

// K1: wt[b,t] = sigmoid(dot(x[b,t,:], w) + bias). One wave (64 lanes) per row.
__global__ __launch_bounds__(256) void wt_kernel(const float* __restrict__ x,
                                                 const float* __restrict__ w,
                                                 const float* __restrict__ bias,
                                                 float* __restrict__ wt) {
    int gid  = blockIdx.x * 256 + threadIdx.x;
    int row  = gid >> 6;    // [0, B*T)
    int lane = gid & 63;
    const float* xr = x + (size_t)row * FF + lane * 8;
    const float* wr = w + lane * 8;
    float4 a0 = *(const float4*)xr;
    float4 a1 = *(const float4*)(xr + 4);
    float4 w0 = *(const float4*)wr;
    float4 w1 = *(const float4*)(wr + 4);
    float s = a0.x * w0.x + a0.y * w0.y + a0.z * w0.z + a0.w * w0.w
            + a1.x * w1.x + a1.y * w1.y + a1.z * w1.z + a1.w * w1.w;
#pragma unroll
    for (int off = 32; off > 0; off >>= 1) s += __shfl_xor(s, off, 64);
    if (lane == 0) {
        float z = s + bias[0];
        wt[row] = 1.0f / (1.0f + expf(-z));
    }
}

// K2: one WAVE per batch. Valley detect + wave-scan compaction, no barriers.
__global__ __launch_bounds__(64) void seg_kernel(const float* __restrict__ wt,
                                                 int* __restrict__ starts,
                                                 int* __restrict__ ends,
                                                 int* __restrict__ counts) {
    int b    = blockIdx.x;
    int lane = threadIdx.x;              // 0..63, 32 consecutive positions each
    const float* wrow = wt + b * TT;
    float v[32];
    const float4* p = (const float4*)(wrow + lane * 32);
#pragma unroll
    for (int k = 0; k < 8; ++k) {
        float4 f = p[k];
        v[4*k] = f.x; v[4*k+1] = f.y; v[4*k+2] = f.z; v[4*k+3] = f.w;
    }
    float left  = __shfl_up(v[31], 1, 64);
    float right = __shfl_down(v[0], 1, 64);
    unsigned int flags = 0;
#pragma unroll
    for (int k = 0; k < 32; ++k) {
        int t = lane * 32 + k;
        float prev = (k == 0)  ? left  : v[k - 1];
        float next = (k == 31) ? right : v[k + 1];
        bool val = (t > 0) && (t < TT - 1) && (v[k] < prev) && (v[k] < next);
        if (val) flags |= (1u << k);
    }
    int cnt = __popc(flags);
    int inc = cnt;
#pragma unroll
    for (int off = 1; off < 64; off <<= 1) {
        int y = __shfl_up(inc, off, 64);
        if (lane >= off) inc += y;
    }
    int total = __shfl(inc, 63, 64);
    int r = inc - cnt;
    int* sb = starts + b * TT;
    int* eb = ends + b * TT;
    unsigned int f = flags;
    while (f) {
        int k = __ffs(f) - 1;
        f &= f - 1;
        int t = lane * 32 + k;
        sb[r + 1] = t;
        eb[r] = t + 2;                   // t <= 2046 -> t+2 <= TT
        ++r;
    }
    if (lane == 0) {
        sb[0] = 0;
        eb[total] = TT;
        counts[b] = total + 1;
    }
}

// K3: partitioned pool + zero + mask.
//  [0, PAIR_BLOCKS): rows j<1024, 1 wave per ROW PAIR (2p, 2p+1) over the contiguous
//    union span [starts[2p], ends[2p+1]) with predicated dual accumulation.
//  [PAIR_BLOCKS, +ZERO_BLOCKS): rows j>=1024, pure NT zero stores.
//  [.., +MASK_BLOCKS): new_mask from counts[].
__global__ __launch_bounds__(256) void pool_kernel(const float* __restrict__ x,
                                                   const float* __restrict__ wt,
                                                   const int* __restrict__ starts,
                                                   const int* __restrict__ ends,
                                                   const int* __restrict__ counts,
                                                   const int* __restrict__ seq_len,
                                                   float* __restrict__ out,
                                                   float* __restrict__ mask_out) {
    int blk = blockIdx.x;
    int tid = threadIdx.x;
    v4f zero = (v4f)(0.f);

    if (blk >= PAIR_BLOCKS + ZERO_BLOCKS) {
        // ---- mask ----
        int idx = (blk - PAIR_BLOCKS - ZERO_BLOCKS) * 256 + tid;  // [0, 8192)
        int maxc = 0;
#pragma unroll
        for (int i = 0; i < BB; ++i) maxc = max(maxc, counts[i]);
        float len0 = (float)min(seq_len[0], TT);
#pragma unroll
        for (int r = 0; r < 4; ++r) {
            int i = idx + r * 8192;
            int b = i >> 11, t = i & (TT - 1);
            int nl = (int)((float)min(seq_len[b], TT) / len0 * (float)maxc);
            mask_out[i] = (t < nl) ? 1.0f : 0.0f;
        }
        return;
    }

    if (blk >= PAIR_BLOCKS) {
        // ---- zero region: rows j in [1024, 2048), 16 rows per block ----
        int zb = blk - PAIR_BLOCKS;
        int b  = zb >> 6;
        int j0 = 1024 + (zb & 63) * 16;
        float* base = out + ((size_t)(b * TT + j0) * FF);
        v4f* dst = (v4f*)base + tid * 2;
        __builtin_nontemporal_store(zero, dst);
        __builtin_nontemporal_store(zero, dst + 1);
        return;
    }

    // ---- paired pool: 4 waves/block, rows jA=2p, jB=2p+1, p in [0,512) per batch ----
    int b    = blk >> 7;                  // 128 blocks per batch
    int wv   = tid >> 6;
    int lane = tid & 63;
    int p    = (blk & 127) * 4 + wv;      // pair index
    int jA   = p * 2;
    int jB   = jA + 1;
    int rowA = b * TT + jA;
    float* orowA = out + (size_t)rowA * FF + lane * 8;
    float* orowB = orowA + FF;

    int cb = counts[b];
    v4f accA0 = (v4f)(0.f), accA1 = (v4f)(0.f);
    v4f accB0 = (v4f)(0.f), accB1 = (v4f)(0.f);
    if (jA < cb) {
        bool hasB = (jB < cb);
        int sA = __builtin_amdgcn_readfirstlane(starts[rowA]);
        int eA = __builtin_amdgcn_readfirstlane(ends[rowA]);
        int sB = hasB ? __builtin_amdgcn_readfirstlane(starts[rowA + 1]) : eA;
        int eU = hasB ? __builtin_amdgcn_readfirstlane(ends[rowA + 1]) : eA;
        const float* xb   = x + (size_t)b * TT * FF + lane * 8;
        const float* wrow = wt + b * TT;
        float denA = 0.f, denB = 0.f;
        for (int t = sA; t < eU; t += 4) {
#pragma unroll
            for (int k = 0; k < 4; ++k) {
                int tt = t + k;
                bool in = (tt < eU);
                int  ti = in ? tt : sA;
                float wraw = wrow[ti];
                float wA = (in && tt < eA)  ? wraw : 0.f;
                float wB = (in && tt >= sB) ? wraw : 0.f;
                const v4f* pp = (const v4f*)(xb + (size_t)ti * FF);
                v4f v0 = pp[0], v1 = pp[1];
                accA0 += wA * v0; accA1 += wA * v1;
                accB0 += wB * v0; accB1 += wB * v1;
                denA += wA; denB += wB;
            }
        }
        float invA = 1.0f / fmaxf(denA, 1e-6f);
        float invB = 1.0f / fmaxf(denB, 1e-6f);
        accA0 *= invA; accA1 *= invA;
        accB0 *= invB; accB1 *= invB;     // hasB==false -> accB stays 0
    }
    __builtin_nontemporal_store(accA0, (v4f*)orowA);
    __builtin_nontemporal_store(accA1, (v4f*)(orowA + 4));
    __builtin_nontemporal_store(accB0, (v4f*)orowB);
    __builtin_nontemporal_store(accB1, (v4f*)(orowB + 4));
}

extern "C" void kernel_launch(void* const* d_in, const int* in_sizes, int n_in,
                              void* d_out, int out_size, void* d_ws, size_t ws_size,
                              hipStream_t stream) {
    const float* x       = (const float*)d_in[0];
    const float* w_aggr  = (const float*)d_in[1];
    const float* b_aggr  = (const float*)d_in[2];
    const int*   seq_len = (const int*)d_in[3];

    float* pooled = (float*)d_out;
    float* mask   = (float*)d_out + (size_t)BB * TT * FF;

    float* wt    = (float*)d_ws;
    int* starts  = (int*)((char*)d_ws + (size_t)BB * TT * 4);
    int* ends    = starts + BB * TT;
    int* counts  = ends + BB * TT;

    wt_kernel<<<(BB * TT) / 4, 256, 0, stream>>>(x, w_aggr, b_aggr, wt);
    seg_kernel<<<BB, 64, 0, stream>>>(wt, starts, ends, counts);
    pool_kernel<<<PAIR_BLOCKS + ZERO_BLOCKS + MASK_BLOCKS, 256, 0, stream>>>(
        x, wt, starts, ends, counts, seq_len, pooled, mask);
}

// Round 9
// 129.426 us; speedup vs baseline: 5.9951x; 1.0068x over previous
//
#include <hip/hip_runtime.h>
#include <math.h>

#define BB 16
#define TT 2048
#define FF 512

#define ACTIVE_BLOCKS 8192   // 32768 waves: 1 wave per (row j<1024, feature-half)
#define ZERO_BLOCKS   1024   // rows j in [1024,2048): always zero (counts <= 1024)
#define MASK_BLOCKS   32

typedef float v4f __attribute__((ext_vector_type(4)));

// K1: wt[b,t] = sigmoid(dot(x[b,t,:], w) + bias). One wave (64 lanes) per row.
__global__ __launch_bounds__(256) void wt_kernel(const float* __restrict__ x,
                                                 const float* __restrict__ w,
                                                 const float* __restrict__ bias,
                                                 float* __restrict__ wt) {
    int gid  = blockIdx.x * 256 + threadIdx.x;
    int row  = gid >> 6;    // [0, B*T)
    int lane = gid & 63;
    const float* xr = x + (size_t)row * FF + lane * 8;
    const float* wr = w + lane * 8;
    float4 a0 = *(const float4*)xr;
    float4 a1 = *(const float4*)(xr + 4);
    float4 w0 = *(const float4*)wr;
    float4 w1 = *(const float4*)(wr + 4);
    float s = a0.x * w0.x + a0.y * w0.y + a0.z * w0.z + a0.w * w0.w
            + a1.x * w1.x + a1.y * w1.y + a1.z * w1.z + a1.w * w1.w;
#pragma unroll
    for (int off = 32; off > 0; off >>= 1) s += __shfl_xor(s, off, 64);
    if (lane == 0) {
        float z = s + bias[0];
        wt[row] = 1.0f / (1.0f + expf(-z));
    }
}

// K2: one WAVE per batch. Valley detect + wave-scan compaction, no barriers.
__global__ __launch_bounds__(64) void seg_kernel(const float* __restrict__ wt,
                                                 int* __restrict__ starts,
                                                 int* __restrict__ ends,
                                                 int* __restrict__ counts) {
    int b    = blockIdx.x;
    int lane = threadIdx.x;              // 0..63, 32 consecutive positions each
    const float* wrow = wt + b * TT;
    float v[32];
    const float4* p = (const float4*)(wrow + lane * 32);
#pragma unroll
    for (int k = 0; k < 8; ++k) {
        float4 f = p[k];
        v[4*k] = f.x; v[4*k+1] = f.y; v[4*k+2] = f.z; v[4*k+3] = f.w;
    }
    float left  = __shfl_up(v[31], 1, 64);
    float right = __shfl_down(v[0], 1, 64);
    unsigned int flags = 0;
#pragma unroll
    for (int k = 0; k < 32; ++k) {
        int t = lane * 32 + k;
        float prev = (k == 0)  ? left  : v[k - 1];
        float next = (k == 31) ? right : v[k + 1];
        bool val = (t > 0) && (t < TT - 1) && (v[k] < prev) && (v[k] < next);
        if (val) flags |= (1u << k);
    }
    int cnt = __popc(flags);
    int inc = cnt;
#pragma unroll
    for (int off = 1; off < 64; off <<= 1) {
        int y = __shfl_up(inc, off, 64);
        if (lane >= off) inc += y;
    }
    int total = __shfl(inc, 63, 64);
    int r = inc - cnt;
    int* sb = starts + b * TT;
    int* eb = ends + b * TT;
    unsigned int f = flags;
    while (f) {
        int k = __ffs(f) - 1;
        f &= f - 1;
        int t = lane * 32 + k;
        sb[r + 1] = t;
        eb[r] = t + 2;                   // t <= 2046 -> t+2 <= TT
        ++r;
    }
    if (lane == 0) {
        sb[0] = 0;
        eb[total] = TT;
        counts[b] = total + 1;
    }
}

// K3: partitioned pool + zero + mask.
//  [0, ACTIVE_BLOCKS): 1 wave per (row j<1024, half). Lane covers 4 floats; unroll-8.
//  [ACTIVE_BLOCKS, +ZERO_BLOCKS): rows j>=1024, pure NT zero stores.
//  [.., +MASK_BLOCKS): new_mask from counts[].
__global__ __launch_bounds__(256) void pool_kernel(const float* __restrict__ x,
                                                   const float* __restrict__ wt,
                                                   const int* __restrict__ starts,
                                                   const int* __restrict__ ends,
                                                   const int* __restrict__ counts,
                                                   const int* __restrict__ seq_len,
                                                   float* __restrict__ out,
                                                   float* __restrict__ mask_out) {
    int blk = blockIdx.x;
    int tid = threadIdx.x;
    v4f zero = (v4f)(0.f);

    if (blk >= ACTIVE_BLOCKS + ZERO_BLOCKS) {
        // ---- mask ----
        int idx = (blk - ACTIVE_BLOCKS - ZERO_BLOCKS) * 256 + tid;  // [0, 8192)
        int maxc = 0;
#pragma unroll
        for (int i = 0; i < BB; ++i) maxc = max(maxc, counts[i]);
        float len0 = (float)min(seq_len[0], TT);
#pragma unroll
        for (int r = 0; r < 4; ++r) {
            int i = idx + r * 8192;
            int b = i >> 11, t = i & (TT - 1);
            int nl = (int)((float)min(seq_len[b], TT) / len0 * (float)maxc);
            mask_out[i] = (t < nl) ? 1.0f : 0.0f;
        }
        return;
    }

    if (blk >= ACTIVE_BLOCKS) {
        // ---- zero region: rows j in [1024, 2048), 16 rows per block ----
        int zb = blk - ACTIVE_BLOCKS;
        int b  = zb >> 6;
        int j0 = 1024 + (zb & 63) * 16;
        float* base = out + ((size_t)(b * TT + j0) * FF);
        v4f* dst = (v4f*)base + tid * 2;
        __builtin_nontemporal_store(zero, dst);
        __builtin_nontemporal_store(zero, dst + 1);
        return;
    }

    // ---- active pool: wave = (row, half); 2 consecutive waves share a row ----
    int wv    = tid >> 6;
    int lane  = tid & 63;
    int aw    = blk * 4 + wv;            // [0, 32768)
    int rowid = aw >> 1;                 // [0, 16384)
    int half  = aw & 1;
    int b     = rowid >> 10;
    int j     = rowid & 1023;
    int row   = b * TT + j;
    int fo    = half * 256 + lane * 4;   // feature offset of this lane's v4f

    v4f acc = (v4f)(0.f);
    if (j < counts[b]) {
        int s = __builtin_amdgcn_readfirstlane(starts[row]);
        int e = __builtin_amdgcn_readfirstlane(ends[row]);
        const float* xb   = x + (size_t)b * TT * FF + fo;
        const float* wrow = wt + b * TT;
        float den = 0.f;
        for (int t = s; t < e; t += 8) {
            int   ii[8];
            float ww[8];
#pragma unroll
            for (int k = 0; k < 8; ++k) {
                int tt = t + k;
                bool in = (tt < e);
                ii[k] = in ? tt : t;
                ww[k] = in ? wrow[ii[k]] : 0.f;
            }
#pragma unroll
            for (int k = 0; k < 8; ++k) {
                const v4f* p = (const v4f*)(xb + (size_t)ii[k] * FF);
                v4f v0 = p[0];
                acc += ww[k] * v0;
                den += ww[k];
            }
        }
        acc *= 1.0f / fmaxf(den, 1e-6f);
    }
    float* orow = out + (size_t)row * FF + fo;
    __builtin_nontemporal_store(acc, (v4f*)orow);
}

extern "C" void kernel_launch(void* const* d_in, const int* in_sizes, int n_in,
                              void* d_out, int out_size, void* d_ws, size_t ws_size,
                              hipStream_t stream) {
    const float* x       = (const float*)d_in[0];
    const float* w_aggr  = (const float*)d_in[1];
    const float* b_aggr  = (const float*)d_in[2];
    const int*   seq_len = (const int*)d_in[3];

    float* pooled = (float*)d_out;
    float* mask   = (float*)d_out + (size_t)BB * TT * FF;

    float* wt    = (float*)d_ws;
    int* starts  = (int*)((char*)d_ws + (size_t)BB * TT * 4);
    int* ends    = starts + BB * TT;
    int* counts  = ends + BB * TT;

    wt_kernel<<<(BB * TT) / 4, 256, 0, stream>>>(x, w_aggr, b_aggr, wt);
    seg_kernel<<<BB, 64, 0, stream>>>(wt, starts, ends, counts);
    pool_kernel<<<ACTIVE_BLOCKS + ZERO_BLOCKS + MASK_BLOCKS, 256, 0, stream>>>(
        x, wt, starts, ends, counts, seq_len, pooled, mask);
}